// Round 1
// baseline (618.965 us; speedup 1.0000x reference)
//
#include <hip/hip_runtime.h>
#include <math.h>

#define D 64
#define EPSN 1e-12f

// Orderable-uint encoding for float atomicMax: unsigned compare == float compare.
__device__ __forceinline__ unsigned enc_f(float f) {
    unsigned b = __float_as_uint(f);
    return (b & 0x80000000u) ? ~b : (b | 0x80000000u);
}
__device__ __forceinline__ float dec_f(unsigned e) {
    unsigned b = (e & 0x80000000u) ? (e ^ 0x80000000u) : ~e;
    return __uint_as_float(b);
}

// K1: one wave (64 lanes) per node row: row-L2-normalize x -> xn; zero sq; init amax with self-loop alpha = beta*1
__global__ void k_node_init(const float* __restrict__ x, float* __restrict__ xn,
                            float* __restrict__ sq, const float* __restrict__ beta,
                            unsigned* __restrict__ amax, int N) {
    int wid = (blockIdx.x * blockDim.x + threadIdx.x) >> 6;
    int lane = threadIdx.x & 63;
    if (wid >= N) return;
    float v = x[(size_t)wid * D + lane];
    float s = v * v;
    #pragma unroll
    for (int off = 32; off; off >>= 1) s += __shfl_xor(s, off);
    float inv = 1.0f / fmaxf(sqrtf(s), EPSN);
    xn[(size_t)wid * D + lane] = v * inv;
    if (lane == 0) {
        sq[wid] = 0.0f;
        amax[wid] = enc_f(beta[0]);
    }
}

// K2: per-source-node sum of edge_attr^2
__global__ void k_edge_sq(const int* __restrict__ row, const float* __restrict__ ea,
                          float* __restrict__ sq, int E) {
    int e = blockIdx.x * blockDim.x + threadIdx.x;
    if (e >= E) return;
    float a = ea[e];
    atomicAdd(&sq[row[e]], a * a);
}

// K3: inv_norm = 1/max(sqrt(sq), eps)  (in-place on sq buffer)
__global__ void k_node_inv(float* __restrict__ sq, int N) {
    int i = blockIdx.x * blockDim.x + threadIdx.x;
    if (i >= N) return;
    sq[i] = 1.0f / fmaxf(sqrtf(sq[i]), EPSN);
}

// K4: segment max of alpha = beta * ea * inv_norm[row]
__global__ void k_edge_amax(const int* __restrict__ row, const float* __restrict__ ea,
                            const float* __restrict__ inv, const float* __restrict__ beta,
                            unsigned* __restrict__ amax, int E) {
    int e = blockIdx.x * blockDim.x + threadIdx.x;
    if (e >= E) return;
    int r = row[e];
    float alpha = beta[0] * ea[e] * inv[r];
    atomicMax(&amax[r], enc_f(alpha));
}

// K5: denom init with the self-loop term exp(beta - amax)
__global__ void k_node_denom(const unsigned* __restrict__ amax, const float* __restrict__ beta,
                             float* __restrict__ denom, int N) {
    int i = blockIdx.x * blockDim.x + threadIdx.x;
    if (i >= N) return;
    denom[i] = expf(beta[0] - dec_f(amax[i]));
}

// K6: e = exp(alpha - amax[row]); store; accumulate denom
__global__ void k_edge_exp(const int* __restrict__ row, const float* __restrict__ ea,
                           const float* __restrict__ inv, const float* __restrict__ beta,
                           const unsigned* __restrict__ amax, float* __restrict__ eexp,
                           float* __restrict__ denom, int E) {
    int e = blockIdx.x * blockDim.x + threadIdx.x;
    if (e >= E) return;
    int r = row[e];
    float alpha = beta[0] * ea[e] * inv[r];
    float ev = expf(alpha - dec_f(amax[r]));
    eexp[e] = ev;
    atomicAdd(&denom[r], ev);
}

// K7: out = (1 + eps + alpha_self) * xn   (residual + self-loop contribution fused)
__global__ void k_out_init(const float* __restrict__ xn, const unsigned* __restrict__ amax,
                           const float* __restrict__ denom, const float* __restrict__ beta,
                           const float* __restrict__ eps, float* __restrict__ out, int total) {
    int idx = blockIdx.x * blockDim.x + threadIdx.x;
    if (idx >= total) return;
    int i = idx >> 6;
    float selfw = expf(beta[0] - dec_f(amax[i])) / denom[i];
    out[idx] = (1.0f + eps[0] + selfw) * xn[idx];
}

// K8: one wave per edge: out[row] += (e/denom[row]) * xn[col]  (64 lanes = 64 features)
__global__ void k_scatter(const int* __restrict__ row, const int* __restrict__ col,
                          const float* __restrict__ eexp, const float* __restrict__ denom,
                          const float* __restrict__ xn, float* __restrict__ out, int E) {
    int wid = (blockIdx.x * blockDim.x + threadIdx.x) >> 6;
    int lane = threadIdx.x & 63;
    if (wid >= E) return;
    int r = row[wid];
    int c = col[wid];
    float coef = eexp[wid] / denom[r];
    atomicAdd(&out[(size_t)r * D + lane], coef * xn[(size_t)c * D + lane]);
}

extern "C" void kernel_launch(void* const* d_in, const int* in_sizes, int n_in,
                              void* d_out, int out_size, void* d_ws, size_t ws_size,
                              hipStream_t stream) {
    const float* x    = (const float*)d_in[0];
    const int*   ei   = (const int*)d_in[1];
    const float* ea   = (const float*)d_in[2];
    const float* eps  = (const float*)d_in[3];
    const float* beta = (const float*)d_in[4];
    float* out = (float*)d_out;

    int N = in_sizes[0] / D;
    int E = in_sizes[2];
    const int* row = ei;
    const int* col = ei + E;

    char* ws = (char*)d_ws;
    float*    xn    = (float*)ws;    ws += (size_t)N * D * sizeof(float);
    float*    sqinv = (float*)ws;    ws += (size_t)N * sizeof(float);
    unsigned* amax  = (unsigned*)ws; ws += (size_t)N * sizeof(unsigned);
    float*    denom = (float*)ws;    ws += (size_t)N * sizeof(float);
    float*    eexp  = (float*)ws;

    const int B = 256;
    int node_wave_blocks = (N * (D / 1) + (B / 64) * 64 - 1) / ((B / 64) * 64);  // N waves
    node_wave_blocks = (N + (B / 64) - 1) / (B / 64);
    int node_blocks = (N + B - 1) / B;
    int edge_blocks = (E + B - 1) / B;
    int scat_blocks = (E + (B / 64) - 1) / (B / 64);
    int elem_blocks = (N * D + B - 1) / B;

    k_node_init<<<node_wave_blocks, B, 0, stream>>>(x, xn, sqinv, beta, amax, N);
    k_edge_sq<<<edge_blocks, B, 0, stream>>>(row, ea, sqinv, E);
    k_node_inv<<<node_blocks, B, 0, stream>>>(sqinv, N);
    k_edge_amax<<<edge_blocks, B, 0, stream>>>(row, ea, sqinv, beta, amax, E);
    k_node_denom<<<node_blocks, B, 0, stream>>>(amax, beta, denom, N);
    k_edge_exp<<<edge_blocks, B, 0, stream>>>(row, ea, sqinv, beta, amax, eexp, denom, E);
    k_out_init<<<elem_blocks, B, 0, stream>>>(xn, amax, denom, beta, eps, out, N * D);
    k_scatter<<<scat_blocks, B, 0, stream>>>(row, col, eexp, denom, xn, out, E);
}

// Round 2
// 437.535 us; speedup vs baseline: 1.4147x; 1.4147x over previous
//
#include <hip/hip_runtime.h>
#include <math.h>

#define D 64
#define EPSN 1e-12f
#define SCAN_B 256

// ---------- K1: wave per node: xn = x / max(||x||,eps) ----------
__global__ void k_node_xn(const float* __restrict__ x, float* __restrict__ xn, int N) {
    int wid  = (blockIdx.x * blockDim.x + threadIdx.x) >> 6;
    int lane = threadIdx.x & 63;
    if (wid >= N) return;
    float v = x[(size_t)wid * D + lane];
    float s = v * v;
    #pragma unroll
    for (int off = 32; off; off >>= 1) s += __shfl_xor(s, off);
    float inv = 1.0f / fmaxf(sqrtf(s), EPSN);
    xn[(size_t)wid * D + lane] = v * inv;
}

// ---------- K2: histogram degrees + per-row sum of ea^2 ----------
__global__ void k_edge_hist(const int* __restrict__ row, const float* __restrict__ ea,
                            int* __restrict__ deg, float* __restrict__ sq, int E) {
    int e = blockIdx.x * blockDim.x + threadIdx.x;
    if (e >= E) return;
    int r = row[e];
    float a = ea[e];
    atomicAdd(&deg[r], 1);
    atomicAdd(&sq[r], a * a);
}

// ---------- K3: per-block exclusive scan of deg -> rs (local), block sums ----------
__global__ void k_scan1(const int* __restrict__ deg, int* __restrict__ rs,
                        int* __restrict__ bsums, int N) {
    __shared__ int sm[SCAN_B];
    int i = blockIdx.x * SCAN_B + threadIdx.x;
    int v = (i < N) ? deg[i] : 0;
    sm[threadIdx.x] = v;
    __syncthreads();
    // Hillis-Steele inclusive scan
    for (int off = 1; off < SCAN_B; off <<= 1) {
        int add = (threadIdx.x >= off) ? sm[threadIdx.x - off] : 0;
        __syncthreads();
        sm[threadIdx.x] += add;
        __syncthreads();
    }
    if (i < N) rs[i] = sm[threadIdx.x] - v;          // exclusive
    if (threadIdx.x == SCAN_B - 1) bsums[blockIdx.x] = sm[threadIdx.x];
}

// ---------- K4: single-block exclusive scan of block sums (in place) ----------
__global__ void k_scan2(int* __restrict__ bsums, int NB) {
    __shared__ int sm[1024];
    int t = threadIdx.x;
    int v = (t < NB) ? bsums[t] : 0;
    sm[t] = v;
    __syncthreads();
    for (int off = 1; off < 1024; off <<= 1) {
        int add = (t >= off) ? sm[t - off] : 0;
        __syncthreads();
        sm[t] += add;
        __syncthreads();
    }
    if (t < NB) bsums[t] = sm[t] - v;                // exclusive
}

// ---------- K5: add block offsets; init cursor; inv-norm; rs[N]=E ----------
__global__ void k_scan3(int* __restrict__ rs, const int* __restrict__ bsums,
                        int* __restrict__ cursor, float* __restrict__ sq, int N, int E) {
    int i = blockIdx.x * blockDim.x + threadIdx.x;
    if (i == 0) rs[N] = E;
    if (i >= N) return;
    int v = rs[i] + bsums[i / SCAN_B];
    rs[i] = v;
    cursor[i] = v;
    sq[i] = 1.0f / fmaxf(sqrtf(sq[i]), EPSN);        // sq now holds inv_norm
}

// ---------- K6: bucket-scatter edges into CSR order: alpha & col ----------
__global__ void k_build(const int* __restrict__ row, const int* __restrict__ col,
                        const float* __restrict__ ea, const float* __restrict__ inv,
                        const float* __restrict__ beta,
                        int* __restrict__ cursor, float* __restrict__ alpha_s,
                        int* __restrict__ col_s, int E) {
    int e = blockIdx.x * blockDim.x + threadIdx.x;
    if (e >= E) return;
    int r = row[e];
    int pos = atomicAdd(&cursor[r], 1);
    alpha_s[pos] = beta[0] * ea[e] * inv[r];
    col_s[pos]   = col[e];
}

// ---------- K7: fused segment softmax + SpMM + residual, wave per row ----------
__global__ void k_row_fused(const int* __restrict__ rs, const float* __restrict__ alpha_s,
                            const int* __restrict__ col_s, const float* __restrict__ xn,
                            const float* __restrict__ beta, const float* __restrict__ eps,
                            float* __restrict__ out, int N) {
    int wid  = (blockIdx.x * blockDim.x + threadIdx.x) >> 6;
    int lane = threadIdx.x & 63;
    if (wid >= N) return;
    int s = rs[wid];
    int t = rs[wid + 1];
    float bv = beta[0];

    // segment max (self-loop alpha = beta included via init)
    float m = bv;
    for (int k = s + lane; k < t; k += 64) m = fmaxf(m, alpha_s[k]);
    #pragma unroll
    for (int off = 32; off; off >>= 1) m = fmaxf(m, __shfl_xor(m, off));

    // segment sum of exp
    float dsum = 0.0f;
    for (int k = s + lane; k < t; k += 64) dsum += expf(alpha_s[k] - m);
    #pragma unroll
    for (int off = 32; off; off >>= 1) dsum += __shfl_xor(dsum, off);
    float selfe = expf(bv - m);
    float invden = 1.0f / (dsum + selfe);

    // PV: sequential over this row's edges, coalesced 256B gathers
    float acc = 0.0f;
    for (int k = s; k < t; ++k) {
        float coef = expf(alpha_s[k] - m) * invden;
        int   c    = col_s[k];
        acc += coef * xn[(size_t)c * D + lane];
    }

    float selfw = selfe * invden;
    out[(size_t)wid * D + lane] = (1.0f + eps[0] + selfw) * xn[(size_t)wid * D + lane] + acc;
}

extern "C" void kernel_launch(void* const* d_in, const int* in_sizes, int n_in,
                              void* d_out, int out_size, void* d_ws, size_t ws_size,
                              hipStream_t stream) {
    const float* x    = (const float*)d_in[0];
    const int*   ei   = (const int*)d_in[1];
    const float* ea   = (const float*)d_in[2];
    const float* eps  = (const float*)d_in[3];
    const float* beta = (const float*)d_in[4];
    float* out = (float*)d_out;

    int N = in_sizes[0] / D;
    int E = in_sizes[2];
    const int* row = ei;
    const int* col = ei + E;

    char* ws = (char*)d_ws;
    float* xn      = (float*)ws;  ws += (size_t)N * D * sizeof(float);
    float* sqinv   = (float*)ws;  ws += (size_t)N * sizeof(float);   // sq, then inv_norm
    int*   deg_cur = (int*)ws;    ws += (size_t)N * sizeof(int);     // deg, then cursor
    int*   rs      = (int*)ws;    ws += (size_t)(N + 1) * sizeof(int);
    int*   bsums   = (int*)ws;    ws += 1024 * sizeof(int);
    float* alpha_s = (float*)ws;  ws += (size_t)E * sizeof(float);
    int*   col_s   = (int*)ws;

    // zero sq + deg (adjacent region)
    hipMemsetAsync(sqinv, 0, (size_t)N * 2 * sizeof(int), stream);

    const int B = 256;
    int wave_blocks = (N + (B / 64) - 1) / (B / 64);   // one wave per node
    int node_blocks = (N + B - 1) / B;
    int edge_blocks = (E + B - 1) / B;
    int NB = (N + SCAN_B - 1) / SCAN_B;                // 391 for N=100000

    k_node_xn  <<<wave_blocks, B, 0, stream>>>(x, xn, N);
    k_edge_hist<<<edge_blocks, B, 0, stream>>>(row, ea, deg_cur, sqinv, E);
    k_scan1    <<<NB, SCAN_B, 0, stream>>>(deg_cur, rs, bsums, N);
    k_scan2    <<<1, 1024, 0, stream>>>(bsums, NB);
    k_scan3    <<<node_blocks, B, 0, stream>>>(rs, bsums, deg_cur, sqinv, N, E);
    k_build    <<<edge_blocks, B, 0, stream>>>(row, col, ea, sqinv, beta, deg_cur,
                                               alpha_s, col_s, E);
    k_row_fused<<<wave_blocks, B, 0, stream>>>(rs, alpha_s, col_s, xn, beta, eps, out, N);
}

// Round 3
// 427.888 us; speedup vs baseline: 1.4466x; 1.0225x over previous
//
#include <hip/hip_runtime.h>
#include <math.h>

#define D 64
#define EPSN 1e-12f
#define SCAN_B 256

// ---------- K1: wave per node: xnh = bf16(x / max(||x||,eps)) ----------
__global__ void k_node_xn(const float* __restrict__ x, unsigned short* __restrict__ xnh, int N) {
    int wid  = (blockIdx.x * blockDim.x + threadIdx.x) >> 6;
    int lane = threadIdx.x & 63;
    if (wid >= N) return;
    float v = x[(size_t)wid * D + lane];
    float s = v * v;
    #pragma unroll
    for (int off = 32; off; off >>= 1) s += __shfl_xor(s, off);
    float inv = 1.0f / fmaxf(sqrtf(s), EPSN);
    float xv = v * inv;
    unsigned u = __float_as_uint(xv);
    u = (u + 0x7FFFu + ((u >> 16) & 1u)) >> 16;      // RNE fp32 -> bf16
    xnh[(size_t)wid * D + lane] = (unsigned short)u;
}

// ---------- K2: histogram degrees + per-row sum of ea^2 ----------
__global__ void k_edge_hist(const int* __restrict__ row, const float* __restrict__ ea,
                            int* __restrict__ deg, float* __restrict__ sq, int E) {
    int e = blockIdx.x * blockDim.x + threadIdx.x;
    if (e >= E) return;
    int r = row[e];
    float a = ea[e];
    atomicAdd(&deg[r], 1);
    atomicAdd(&sq[r], a * a);
}

// ---------- K3: per-block exclusive scan of deg -> rs (local), block sums ----------
__global__ void k_scan1(const int* __restrict__ deg, int* __restrict__ rs,
                        int* __restrict__ bsums, int N) {
    __shared__ int sm[SCAN_B];
    int i = blockIdx.x * SCAN_B + threadIdx.x;
    int v = (i < N) ? deg[i] : 0;
    sm[threadIdx.x] = v;
    __syncthreads();
    for (int off = 1; off < SCAN_B; off <<= 1) {
        int add = (threadIdx.x >= off) ? sm[threadIdx.x - off] : 0;
        __syncthreads();
        sm[threadIdx.x] += add;
        __syncthreads();
    }
    if (i < N) rs[i] = sm[threadIdx.x] - v;          // exclusive
    if (threadIdx.x == SCAN_B - 1) bsums[blockIdx.x] = sm[threadIdx.x];
}

// ---------- K4: single-block exclusive scan of block sums (in place) ----------
__global__ void k_scan2(int* __restrict__ bsums, int NB) {
    __shared__ int sm[1024];
    int t = threadIdx.x;
    int v = (t < NB) ? bsums[t] : 0;
    sm[t] = v;
    __syncthreads();
    for (int off = 1; off < 1024; off <<= 1) {
        int add = (t >= off) ? sm[t - off] : 0;
        __syncthreads();
        sm[t] += add;
        __syncthreads();
    }
    if (t < NB) bsums[t] = sm[t] - v;                // exclusive
}

// ---------- K5: add block offsets; init cursor; inv-norm; rs[N]=E ----------
__global__ void k_scan3(int* __restrict__ rs, const int* __restrict__ bsums,
                        int* __restrict__ cursor, float* __restrict__ sq, int N, int E) {
    int i = blockIdx.x * blockDim.x + threadIdx.x;
    if (i == 0) rs[N] = E;
    if (i >= N) return;
    int v = rs[i] + bsums[i / SCAN_B];
    rs[i] = v;
    cursor[i] = v;
    sq[i] = 1.0f / fmaxf(sqrtf(sq[i]), EPSN);        // sq now holds inv_norm
}

// ---------- K6: bucket-scatter: wcol[pos] = {exp(alpha), col} ----------
__global__ void k_build(const int* __restrict__ row, const int* __restrict__ col,
                        const float* __restrict__ ea, const float* __restrict__ inv,
                        const float* __restrict__ beta,
                        int* __restrict__ cursor, float2* __restrict__ wcol, int E) {
    int e = blockIdx.x * blockDim.x + threadIdx.x;
    if (e >= E) return;
    int r = row[e];
    int pos = atomicAdd(&cursor[r], 1);
    float w = __expf(beta[0] * ea[e] * inv[r]);      // alpha bounded by |beta|, no overflow
    wcol[pos] = make_float2(w, __int_as_float(col[e]));
}

// ---------- K7: fused single-pass softmax-SpMM + residual, wave per row ----------
__global__ void k_fused(const int* __restrict__ rs, const float2* __restrict__ wcol,
                        const unsigned short* __restrict__ xnh, const float* __restrict__ x,
                        const float* __restrict__ beta, const float* __restrict__ eps,
                        float* __restrict__ out, int N) {
    int wid  = (blockIdx.x * blockDim.x + threadIdx.x) >> 6;
    int lane = threadIdx.x & 63;
    if (wid >= N) return;
    int s = rs[wid];
    int t = rs[wid + 1];

    float esum = 0.0f;
    float acc  = 0.0f;
    for (int k = s; k < t; ++k) {
        float2 wc = wcol[k];                         // broadcast 8B load
        int c = __float_as_int(wc.y);
        esum += wc.x;
        float xv = __uint_as_float((unsigned)xnh[(size_t)c * D + lane] << 16);
        acc += wc.x * xv;
    }

    // self row: recompute normalized x
    float v = x[(size_t)wid * D + lane];
    float ss = v * v;
    #pragma unroll
    for (int off = 32; off; off >>= 1) ss += __shfl_xor(ss, off);
    float xs = v * (1.0f / fmaxf(sqrtf(ss), EPSN));

    float eb = __expf(beta[0]);
    float invden = 1.0f / (esum + eb);
    out[(size_t)wid * D + lane] = (1.0f + eps[0]) * xs + (acc + eb * xs) * invden;
}

static inline size_t align_up(size_t v, size_t a) { return (v + a - 1) & ~(a - 1); }

extern "C" void kernel_launch(void* const* d_in, const int* in_sizes, int n_in,
                              void* d_out, int out_size, void* d_ws, size_t ws_size,
                              hipStream_t stream) {
    const float* x    = (const float*)d_in[0];
    const int*   ei   = (const int*)d_in[1];
    const float* ea   = (const float*)d_in[2];
    const float* eps  = (const float*)d_in[3];
    const float* beta = (const float*)d_in[4];
    float* out = (float*)d_out;

    int N = in_sizes[0] / D;
    int E = in_sizes[2];
    const int* row = ei;
    const int* col = ei + E;

    char* base = (char*)d_ws;
    size_t off = 0;
    unsigned short* xnh = (unsigned short*)(base + off); off = align_up(off + (size_t)N * D * sizeof(unsigned short), 256);
    float* sqinv        = (float*)(base + off);          off = align_up(off + (size_t)N * sizeof(float), 256);
    int*   deg_cur      = (int*)(base + off);            off = align_up(off + (size_t)N * sizeof(int), 256);
    int*   rs           = (int*)(base + off);            off = align_up(off + (size_t)(N + 1) * sizeof(int), 256);
    int*   bsums        = (int*)(base + off);            off = align_up(off + 1024 * sizeof(int), 256);
    float2* wcol        = (float2*)(base + off);

    // zero sq and deg
    hipMemsetAsync(sqinv, 0, (size_t)N * sizeof(float), stream);
    hipMemsetAsync(deg_cur, 0, (size_t)N * sizeof(int), stream);

    const int B = 256;
    int wave_blocks = (N + (B / 64) - 1) / (B / 64);   // one wave per node
    int node_blocks = (N + B - 1) / B;
    int edge_blocks = (E + B - 1) / B;
    int NB = (N + SCAN_B - 1) / SCAN_B;

    k_node_xn  <<<wave_blocks, B, 0, stream>>>(x, xnh, N);
    k_edge_hist<<<edge_blocks, B, 0, stream>>>(row, ea, deg_cur, sqinv, E);
    k_scan1    <<<NB, SCAN_B, 0, stream>>>(deg_cur, rs, bsums, N);
    k_scan2    <<<1, 1024, 0, stream>>>(bsums, NB);
    k_scan3    <<<node_blocks, B, 0, stream>>>(rs, bsums, deg_cur, sqinv, N, E);
    k_build    <<<edge_blocks, B, 0, stream>>>(row, col, ea, sqinv, beta, deg_cur, wcol, E);
    k_fused    <<<wave_blocks, B, 0, stream>>>(rs, wcol, xnh, x, beta, eps, out, N);
}

// Round 4
// 288.652 us; speedup vs baseline: 2.1443x; 1.4824x over previous
//
#include <hip/hip_runtime.h>
#include <math.h>

#define D 64
#define EPSN 1e-12f
#define SCAN_B 256

__device__ __forceinline__ float bf2f(unsigned short u) {
    return __uint_as_float((unsigned)u << 16);
}
__device__ __forceinline__ unsigned short f2bf(float f) {
    unsigned u = __float_as_uint(f);
    u = (u + 0x7FFFu + ((u >> 16) & 1u)) >> 16;      // RNE fp32 -> bf16
    return (unsigned short)u;
}

// ---------- K1: 16 lanes per row: xnh = bf16(x / max(||x||,eps)), float4/ushort4 ----------
__global__ void k_node_xn(const float4* __restrict__ x4, ushort4* __restrict__ xnh4, int N) {
    int tid = blockIdx.x * blockDim.x + threadIdx.x;
    int r = tid >> 4;
    int g = tid & 15;
    if (r >= N) return;
    float4 v = x4[(size_t)r * 16 + g];
    float s = v.x * v.x + v.y * v.y + v.z * v.z + v.w * v.w;
    #pragma unroll
    for (int off = 8; off; off >>= 1) s += __shfl_xor(s, off);   // 16-lane group reduce
    float inv = 1.0f / fmaxf(sqrtf(s), EPSN);
    ushort4 o;
    o.x = f2bf(v.x * inv); o.y = f2bf(v.y * inv);
    o.z = f2bf(v.z * inv); o.w = f2bf(v.w * inv);
    xnh4[(size_t)r * 16 + g] = o;
}

// ---------- K2: degree histogram only, 4 edges/thread ----------
__global__ void k_hist(const int* __restrict__ row, int* __restrict__ deg, int E) {
    int i = blockIdx.x * blockDim.x + threadIdx.x;
    int e = i * 4;
    if (e + 3 < E) {
        int4 r = *(const int4*)(row + e);
        atomicAdd(&deg[r.x], 1); atomicAdd(&deg[r.y], 1);
        atomicAdd(&deg[r.z], 1); atomicAdd(&deg[r.w], 1);
    } else {
        for (int k = e; k < E; ++k) atomicAdd(&deg[row[k]], 1);
    }
}

// ---------- K3: per-block exclusive scan of deg -> rs (local), block sums ----------
__global__ void k_scan1(const int* __restrict__ deg, int* __restrict__ rs,
                        int* __restrict__ bsums, int N) {
    __shared__ int sm[SCAN_B];
    int i = blockIdx.x * SCAN_B + threadIdx.x;
    int v = (i < N) ? deg[i] : 0;
    sm[threadIdx.x] = v;
    __syncthreads();
    for (int off = 1; off < SCAN_B; off <<= 1) {
        int add = (threadIdx.x >= off) ? sm[threadIdx.x - off] : 0;
        __syncthreads();
        sm[threadIdx.x] += add;
        __syncthreads();
    }
    if (i < N) rs[i] = sm[threadIdx.x] - v;          // exclusive
    if (threadIdx.x == SCAN_B - 1) bsums[blockIdx.x] = sm[threadIdx.x];
}

// ---------- K4: single-block exclusive scan of block sums (in place) ----------
__global__ void k_scan2(int* __restrict__ bsums, int NB) {
    __shared__ int sm[1024];
    int t = threadIdx.x;
    int v = (t < NB) ? bsums[t] : 0;
    sm[t] = v;
    __syncthreads();
    for (int off = 1; off < 1024; off <<= 1) {
        int add = (t >= off) ? sm[t - off] : 0;
        __syncthreads();
        sm[t] += add;
        __syncthreads();
    }
    if (t < NB) bsums[t] = sm[t] - v;                // exclusive
}

// ---------- K5: add block offsets; init cursor; rs[N]=E ----------
__global__ void k_scan3(int* __restrict__ rs, const int* __restrict__ bsums,
                        int* __restrict__ cursor, int N, int E) {
    int i = blockIdx.x * blockDim.x + threadIdx.x;
    if (i == 0) rs[N] = E;
    if (i >= N) return;
    int v = rs[i] + bsums[i / SCAN_B];
    rs[i] = v;
    cursor[i] = v;
}

// ---------- K6: bucket-scatter raw {ea, col} into CSR order ----------
__global__ void k_build(const int* __restrict__ row, const int* __restrict__ col,
                        const float* __restrict__ ea,
                        int* __restrict__ cursor, float2* __restrict__ eacol, int E) {
    int e = blockIdx.x * blockDim.x + threadIdx.x;
    if (e >= E) return;
    int r = row[e];
    int pos = atomicAdd(&cursor[r], 1);
    eacol[pos] = make_float2(ea[e], __int_as_float(col[e]));
}

// ---------- K7: fused row-norm + softmax + SpMM + residual, wave per row, 4-way MLP ----------
__global__ void k_fused(const int* __restrict__ rs, const float2* __restrict__ eacol,
                        const unsigned short* __restrict__ xnh, const float* __restrict__ x,
                        const float* __restrict__ beta, const float* __restrict__ eps,
                        float* __restrict__ out, int N) {
    int wid  = (blockIdx.x * blockDim.x + threadIdx.x) >> 6;
    int lane = threadIdx.x & 63;
    if (wid >= N) return;
    int s = rs[wid];
    int t = rs[wid + 1];
    float bv = beta[0];

    // ||ea_row||: lanes split edges (CSR segment is tiny, stays L1/L2-hot)
    float sqs = 0.0f;
    for (int k = s + lane; k < t; k += 64) { float a = eacol[k].x; sqs = fmaf(a, a, sqs); }
    #pragma unroll
    for (int off = 32; off; off >>= 1) sqs += __shfl_xor(sqs, off);
    float binv = bv / fmaxf(sqrtf(sqs), EPSN);       // beta * inv_norm

    float esum = 0.0f, acc = 0.0f;
    int k = s;
    for (; k + 4 <= t; k += 4) {
        float2 e0 = eacol[k], e1 = eacol[k+1], e2 = eacol[k+2], e3 = eacol[k+3];
        int c0 = __float_as_int(e0.y), c1 = __float_as_int(e1.y);
        int c2 = __float_as_int(e2.y), c3 = __float_as_int(e3.y);
        float x0 = bf2f(xnh[(size_t)c0 * D + lane]);
        float x1 = bf2f(xnh[(size_t)c1 * D + lane]);
        float x2 = bf2f(xnh[(size_t)c2 * D + lane]);
        float x3 = bf2f(xnh[(size_t)c3 * D + lane]);
        float w0 = __expf(binv * e0.x), w1 = __expf(binv * e1.x);
        float w2 = __expf(binv * e2.x), w3 = __expf(binv * e3.x);
        esum += (w0 + w1) + (w2 + w3);
        acc = fmaf(w0, x0, fmaf(w1, x1, fmaf(w2, x2, fmaf(w3, x3, acc))));
    }
    for (; k < t; ++k) {
        float2 e0 = eacol[k];
        float w0 = __expf(binv * e0.x);
        esum += w0;
        acc = fmaf(w0, bf2f(xnh[(size_t)__float_as_int(e0.y) * D + lane]), acc);
    }

    // self row: recompute normalized x in fp32 (keeps residual term accurate)
    float v = x[(size_t)wid * D + lane];
    float ss = v * v;
    #pragma unroll
    for (int off = 32; off; off >>= 1) ss += __shfl_xor(ss, off);
    float xs = v * (1.0f / fmaxf(sqrtf(ss), EPSN));

    float eb = __expf(bv);
    float invden = 1.0f / (esum + eb);
    out[(size_t)wid * D + lane] = (1.0f + eps[0]) * xs + (acc + eb * xs) * invden;
}

static inline size_t align_up(size_t v, size_t a) { return (v + a - 1) & ~(a - 1); }

extern "C" void kernel_launch(void* const* d_in, const int* in_sizes, int n_in,
                              void* d_out, int out_size, void* d_ws, size_t ws_size,
                              hipStream_t stream) {
    const float* x    = (const float*)d_in[0];
    const int*   ei   = (const int*)d_in[1];
    const float* ea   = (const float*)d_in[2];
    const float* eps  = (const float*)d_in[3];
    const float* beta = (const float*)d_in[4];
    float* out = (float*)d_out;

    int N = in_sizes[0] / D;
    int E = in_sizes[2];
    const int* row = ei;
    const int* col = ei + E;

    char* base = (char*)d_ws;
    size_t off = 0;
    unsigned short* xnh = (unsigned short*)(base + off); off = align_up(off + (size_t)N * D * sizeof(unsigned short), 256);
    int*    deg_cur     = (int*)(base + off);            off = align_up(off + (size_t)N * sizeof(int), 256);
    int*    rs          = (int*)(base + off);            off = align_up(off + (size_t)(N + 1) * sizeof(int), 256);
    int*    bsums       = (int*)(base + off);            off = align_up(off + 1024 * sizeof(int), 256);
    float2* eacol       = (float2*)(base + off);

    hipMemsetAsync(deg_cur, 0, (size_t)N * sizeof(int), stream);

    const int B = 256;
    int xn_blocks   = ((size_t)N * 16 + B - 1) / B;
    int node_blocks = (N + B - 1) / B;
    int hist_blocks = ((E + 3) / 4 + B - 1) / B;
    int edge_blocks = (E + B - 1) / B;
    int wave_blocks = (N + (B / 64) - 1) / (B / 64);
    int NB = (N + SCAN_B - 1) / SCAN_B;

    k_node_xn<<<xn_blocks, B, 0, stream>>>((const float4*)x, (ushort4*)xnh, N);
    k_hist   <<<hist_blocks, B, 0, stream>>>(row, deg_cur, E);
    k_scan1  <<<NB, SCAN_B, 0, stream>>>(deg_cur, rs, bsums, N);
    k_scan2  <<<1, 1024, 0, stream>>>(bsums, NB);
    k_scan3  <<<node_blocks, B, 0, stream>>>(rs, bsums, deg_cur, N, E);
    k_build  <<<edge_blocks, B, 0, stream>>>(row, col, ea, deg_cur, eacol, E);
    k_fused  <<<wave_blocks, B, 0, stream>>>(rs, eacol, xnh, x, beta, eps, out, N);
}

// Round 5
// 201.408 us; speedup vs baseline: 3.0732x; 1.4332x over previous
//
#include <hip/hip_runtime.h>
#include <math.h>

#define D 64
#define EPSN 1e-12f
#define SCAN_B 256
#define RPB 128          // rows per bucket
#define RPB_SH 7
#define CH 4096          // edges per phase-1 workgroup
#define NBK_CAP 1024     // scan-padded bucket capacity (NBK=782 for N=100000)

__device__ __forceinline__ float bf2f(unsigned short u) {
    return __uint_as_float((unsigned)u << 16);
}
__device__ __forceinline__ unsigned short f2bf(float f) {
    unsigned u = __float_as_uint(f);
    u = (u + 0x7FFFu + ((u >> 16) & 1u)) >> 16;      // RNE fp32 -> bf16
    return (unsigned short)u;
}

// ---------- K1: 16 lanes per row: xnh = bf16(x / max(||x||,eps)) ----------
__global__ void k_node_xn(const float4* __restrict__ x4, ushort4* __restrict__ xnh4, int N) {
    int tid = blockIdx.x * blockDim.x + threadIdx.x;
    int r = tid >> 4;
    int g = tid & 15;
    if (r >= N) return;
    float4 v = x4[(size_t)r * 16 + g];
    float s = v.x * v.x + v.y * v.y + v.z * v.z + v.w * v.w;
    #pragma unroll
    for (int off = 8; off; off >>= 1) s += __shfl_xor(s, off);
    float inv = 1.0f / fmaxf(sqrtf(s), EPSN);
    ushort4 o;
    o.x = f2bf(v.x * inv); o.y = f2bf(v.y * inv);
    o.z = f2bf(v.z * inv); o.w = f2bf(v.w * inv);
    xnh4[(size_t)r * 16 + g] = o;
}

// ---------- K2: degree histogram, 4 edges/thread ----------
__global__ void k_hist(const int* __restrict__ row, int* __restrict__ deg, int E) {
    int i = blockIdx.x * blockDim.x + threadIdx.x;
    int e = i * 4;
    if (e + 3 < E) {
        int4 r = *(const int4*)(row + e);
        atomicAdd(&deg[r.x], 1); atomicAdd(&deg[r.y], 1);
        atomicAdd(&deg[r.z], 1); atomicAdd(&deg[r.w], 1);
    } else {
        for (int k = e; k < E; ++k) atomicAdd(&deg[row[k]], 1);
    }
}

// ---------- K3: per-block exclusive scan of deg -> rs ----------
__global__ void k_scan1(const int* __restrict__ deg, int* __restrict__ rs,
                        int* __restrict__ bsums, int N) {
    __shared__ int sm[SCAN_B];
    int i = blockIdx.x * SCAN_B + threadIdx.x;
    int v = (i < N) ? deg[i] : 0;
    sm[threadIdx.x] = v;
    __syncthreads();
    for (int off = 1; off < SCAN_B; off <<= 1) {
        int add = (threadIdx.x >= off) ? sm[threadIdx.x - off] : 0;
        __syncthreads();
        sm[threadIdx.x] += add;
        __syncthreads();
    }
    if (i < N) rs[i] = sm[threadIdx.x] - v;
    if (threadIdx.x == SCAN_B - 1) bsums[blockIdx.x] = sm[threadIdx.x];
}

// ---------- K4: single-block scan of block sums ----------
__global__ void k_scan2(int* __restrict__ bsums, int NB) {
    __shared__ int sm[1024];
    int t = threadIdx.x;
    int v = (t < NB) ? bsums[t] : 0;
    sm[t] = v;
    __syncthreads();
    for (int off = 1; off < 1024; off <<= 1) {
        int add = (t >= off) ? sm[t - off] : 0;
        __syncthreads();
        sm[t] += add;
        __syncthreads();
    }
    if (t < NB) bsums[t] = sm[t] - v;
}

// ---------- K5: finalize rs; init bucket cursors to bucket bases ----------
__global__ void k_scan3(int* __restrict__ rs, const int* __restrict__ bsums,
                        int* __restrict__ bcur, int N, int E) {
    int i = blockIdx.x * blockDim.x + threadIdx.x;
    if (i == 0) rs[N] = E;
    if (i >= N) return;
    int v = rs[i] + bsums[i / SCAN_B];
    rs[i] = v;
    if ((i & (RPB - 1)) == 0) bcur[i >> RPB_SH] = v;
}

// ---------- K6: phase-1 LDS multi-split: bucket-grouped {ea, rl|col} ----------
__global__ __launch_bounds__(256) void k_p1(const int* __restrict__ row,
                                            const int* __restrict__ col,
                                            const float* __restrict__ ea,
                                            int* __restrict__ gcur,
                                            float2* __restrict__ p1, int E, int NBK) {
    __shared__ unsigned hist[NBK_CAP];       // becomes loff after in-place scan
    __shared__ unsigned gb[NBK_CAP];
    __shared__ unsigned lcur[NBK_CAP];
    __shared__ float    sea[CH];
    __shared__ unsigned spk[CH];
    __shared__ unsigned short sbk[CH];
    __shared__ unsigned temp[256];

    int tid  = threadIdx.x;
    int base = blockIdx.x * CH;
    int cnt  = min(CH, E - base);

    for (int b = tid; b < NBK_CAP; b += 256) hist[b] = 0;
    __syncthreads();

    int   myrow[16]; int mycol[16]; float myea[16];
    #pragma unroll
    for (int k = 0; k < 16; ++k) {
        int j = tid + k * 256;
        if (j < cnt) {
            int r = row[base + j];
            myrow[k] = r;
            mycol[k] = col[base + j];
            myea[k]  = ea[base + j];
            atomicAdd(&hist[r >> RPB_SH], 1u);
        }
    }
    __syncthreads();

    // reserve contiguous global range per bucket (one atomic per WG-bucket)
    for (int b = tid; b < NBK; b += 256) {
        unsigned c = hist[b];
        gb[b] = c ? (unsigned)atomicAdd(&gcur[b], (int)c) : 0u;
    }
    __syncthreads();

    // exclusive scan of hist[0..1024) in place -> loff
    int t4 = tid * 4;
    unsigned a0 = hist[t4], a1 = hist[t4 + 1], a2 = hist[t4 + 2], a3 = hist[t4 + 3];
    unsigned ts = a0 + a1 + a2 + a3;
    temp[tid] = ts;
    __syncthreads();
    for (int off = 1; off < 256; off <<= 1) {
        unsigned add = (tid >= off) ? temp[tid - off] : 0;
        __syncthreads();
        temp[tid] += add;
        __syncthreads();
    }
    unsigned tb = temp[tid] - ts;
    hist[t4] = tb; hist[t4 + 1] = tb + a0;
    hist[t4 + 2] = tb + a0 + a1; hist[t4 + 3] = tb + a0 + a1 + a2;
    __syncthreads();
    for (int b = tid; b < NBK_CAP; b += 256) lcur[b] = hist[b];
    __syncthreads();

    // scatter into LDS staging, grouped by bucket
    #pragma unroll
    for (int k = 0; k < 16; ++k) {
        int j = tid + k * 256;
        if (j < cnt) {
            int b = myrow[k] >> RPB_SH;
            unsigned rl = (unsigned)(myrow[k] & (RPB - 1));
            unsigned pos = atomicAdd(&lcur[b], 1u);
            sea[pos] = myea[k];
            spk[pos] = (rl << 24) | (unsigned)mycol[k];
            sbk[pos] = (unsigned short)b;
        }
    }
    __syncthreads();

    // coalesced flush: contiguous runs per bucket
    for (int j = tid; j < cnt; j += 256) {
        int b = sbk[j];
        unsigned gpos = gb[b] + (unsigned)j - hist[b];   // hist == loff
        p1[gpos] = make_float2(sea[j], __uint_as_float(spk[j]));
    }
}

// ---------- K7: phase-2 per-bucket: row norms + exact CSR scatter of {w, col} ----------
__global__ __launch_bounds__(256) void k_p2(const int* __restrict__ rs,
                                            const float2* __restrict__ p1,
                                            const float* __restrict__ beta,
                                            float2* __restrict__ wcol, int N) {
    __shared__ float    sqs[RPB];
    __shared__ float    binv[RPB];
    __shared__ unsigned cur[RPB];
    int b = blockIdx.x;
    int rowbase = b << RPB_SH;
    int nrows = min(RPB, N - rowbase);
    int tid = threadIdx.x;
    if (tid < RPB) sqs[tid] = 0.0f;
    if (tid < nrows) cur[tid] = (unsigned)rs[rowbase + tid];
    __syncthreads();
    int s = rs[rowbase];
    int t = rs[rowbase + nrows];
    for (int j = s + tid; j < t; j += 256) {
        float a = p1[j].x;
        unsigned rl = __float_as_uint(p1[j].y) >> 24;
        atomicAdd(&sqs[rl], a * a);
    }
    __syncthreads();
    float bv = beta[0];
    if (tid < RPB) binv[tid] = bv / fmaxf(sqrtf(sqs[tid]), EPSN);
    __syncthreads();
    for (int j = s + tid; j < t; j += 256) {
        float2 p = p1[j];
        unsigned pk = __float_as_uint(p.y);
        unsigned rl = pk >> 24;
        unsigned c  = pk & 0xFFFFFFu;
        float w = __expf(p.x * binv[rl]);
        unsigned pos = atomicAdd(&cur[rl], 1u);
        wcol[pos] = make_float2(w, __uint_as_float(c));
    }
}

// ---------- K8: fused softmax-SpMM + residual, wave per row, 4-way MLP ----------
__global__ void k_fused(const int* __restrict__ rs, const float2* __restrict__ wcol,
                        const unsigned short* __restrict__ xnh, const float* __restrict__ x,
                        const float* __restrict__ beta, const float* __restrict__ eps,
                        float* __restrict__ out, int N) {
    int wid  = (blockIdx.x * blockDim.x + threadIdx.x) >> 6;
    int lane = threadIdx.x & 63;
    if (wid >= N) return;
    int s = rs[wid];
    int t = rs[wid + 1];

    float esum = 0.0f, acc = 0.0f;
    int k = s;
    for (; k + 4 <= t; k += 4) {
        float2 e0 = wcol[k], e1 = wcol[k + 1], e2 = wcol[k + 2], e3 = wcol[k + 3];
        int c0 = __float_as_int(e0.y), c1 = __float_as_int(e1.y);
        int c2 = __float_as_int(e2.y), c3 = __float_as_int(e3.y);
        float x0 = bf2f(xnh[(size_t)c0 * D + lane]);
        float x1 = bf2f(xnh[(size_t)c1 * D + lane]);
        float x2 = bf2f(xnh[(size_t)c2 * D + lane]);
        float x3 = bf2f(xnh[(size_t)c3 * D + lane]);
        esum += (e0.x + e1.x) + (e2.x + e3.x);
        acc = fmaf(e0.x, x0, fmaf(e1.x, x1, fmaf(e2.x, x2, fmaf(e3.x, x3, acc))));
    }
    for (; k < t; ++k) {
        float2 e0 = wcol[k];
        esum += e0.x;
        acc = fmaf(e0.x, bf2f(xnh[(size_t)__float_as_int(e0.y) * D + lane]), acc);
    }

    // self row: fp32 renormalize
    float v = x[(size_t)wid * D + lane];
    float ss = v * v;
    #pragma unroll
    for (int off = 32; off; off >>= 1) ss += __shfl_xor(ss, off);
    float xs = v * (1.0f / fmaxf(sqrtf(ss), EPSN));

    float eb = __expf(beta[0]);
    float invden = 1.0f / (esum + eb);
    out[(size_t)wid * D + lane] = (1.0f + eps[0]) * xs + (acc + eb * xs) * invden;
}

static inline size_t align_up(size_t v, size_t a) { return (v + a - 1) & ~(a - 1); }

extern "C" void kernel_launch(void* const* d_in, const int* in_sizes, int n_in,
                              void* d_out, int out_size, void* d_ws, size_t ws_size,
                              hipStream_t stream) {
    const float* x    = (const float*)d_in[0];
    const int*   ei   = (const int*)d_in[1];
    const float* ea   = (const float*)d_in[2];
    const float* eps  = (const float*)d_in[3];
    const float* beta = (const float*)d_in[4];
    float* out = (float*)d_out;

    int N = in_sizes[0] / D;
    int E = in_sizes[2];
    const int* row = ei;
    const int* col = ei + E;
    int NBK = (N + RPB - 1) >> RPB_SH;

    char* base = (char*)d_ws;
    size_t off = 0;
    unsigned short* xnh = (unsigned short*)(base + off); off = align_up(off + (size_t)N * D * sizeof(unsigned short), 256);
    int*    deg_cur     = (int*)(base + off);            off = align_up(off + (size_t)N * sizeof(int), 256);  // deg, then bucket cursors
    int*    rs          = (int*)(base + off);            off = align_up(off + (size_t)(N + 1) * sizeof(int), 256);
    int*    bsums       = (int*)(base + off);            off = align_up(off + 1024 * sizeof(int), 256);
    float2* p1buf       = (float2*)(base + off);         off = align_up(off + (size_t)E * sizeof(float2), 256);
    float2* wcol        = (float2*)(base + off);

    hipMemsetAsync(deg_cur, 0, (size_t)N * sizeof(int), stream);

    const int B = 256;
    int xn_blocks   = ((size_t)N * 16 + B - 1) / B;
    int node_blocks = (N + B - 1) / B;
    int hist_blocks = ((E + 3) / 4 + B - 1) / B;
    int wave_blocks = (N + (B / 64) - 1) / (B / 64);
    int p1_blocks   = (E + CH - 1) / CH;
    int NB = (N + SCAN_B - 1) / SCAN_B;

    k_node_xn<<<xn_blocks, B, 0, stream>>>((const float4*)x, (ushort4*)xnh, N);
    k_hist   <<<hist_blocks, B, 0, stream>>>(row, deg_cur, E);
    k_scan1  <<<NB, SCAN_B, 0, stream>>>(deg_cur, rs, bsums, N);
    k_scan2  <<<1, 1024, 0, stream>>>(bsums, NB);
    k_scan3  <<<node_blocks, B, 0, stream>>>(rs, bsums, deg_cur, N, E);
    k_p1     <<<p1_blocks, B, 0, stream>>>(row, col, ea, deg_cur, p1buf, E, NBK);
    k_p2     <<<NBK, B, 0, stream>>>(rs, p1buf, beta, wcol, N);
    k_fused  <<<wave_blocks, B, 0, stream>>>(rs, wcol, xnh, x, beta, eps, out, N);
}